// Round 1
// 266.757 us; speedup vs baseline: 1.0340x; 1.0340x over previous
//
#include <hip/hip_runtime.h>

// MetaPolicyTransformer: B=65536,T=20,M=4,D=4,L=3,H=2,FF=16,S=5. N=B*T seqs.
// R7 = R6 + (1) TWO sequences per thread (ILP + SGPR-mov amortization;
// occupancy was ~3.2 waves/SIMD at VGPR=52, so registers are free),
// (2) FFN hidden layer via packed fp16 (v_pk_fma_f16 + v_pk_max_f16 relu,
// b1 pre-packed as h2 pairs in prep), (3) layer loop NOT unrolled to keep
// code size ~1/3 (I$ control).
// Carried from R3-R6: 1 thread = full sequence, uniform s_load weights,
// v_dot2_f32_f16 linear algebra, exp2-domain attention (log2e/sqrt2 folded
// into Wk/bk by prep), no softmax max-subtract (scores bounded).

typedef _Float16 h2 __attribute__((ext_vector_type(2)));

// d_ws word layout (4-byte words; fp32 or half2 per word)
enum {
  WF_CLS  = 0,    // 4   fp32: cls + PE row 0 prefolded
  WF_BQKV = 4,    // 36  fp32 biases, k-part pre-scaled by log2e/sqrt2
  WF_BO   = 40,   // 12
  WF_B2   = 52,   // 12
  H_B1    = 64,   // 24  half2: (l,p) = (b1[2p], b1[2p+1])
  H_QKV   = 88,   // 72  half2: (l,row j,pair p) Wqkv[j][2p],[2p+1]; k rows scaled
  H_WO    = 160,  // 24  half2: (l,i,p)
  H_W1    = 184,  // 96  half2 PAIR-MAJOR: (l,p,d) = (W1[2p][d], W1[2p+1][d])
  H_W2    = 280,  // 96  half2: (l,i,fpair p) W2[i][2p],[2p+1]
  WF_FLAG = 376,  // int: 1 if regional_states fp32
  WF_TOTAL = 377
};

__device__ __forceinline__ float bf2f(unsigned short u) {
  unsigned int x = ((unsigned int)u) << 16;
  float f;
  __builtin_memcpy(&f, &x, 4);
  return f;
}

__device__ __forceinline__ bool is_bf16_packed(const unsigned int* w) {
  int pass = 0;
#pragma unroll
  for (int i = 0; i < 16; ++i) {
    unsigned int lo = w[i] & 0xFFFFu;
    unsigned int e = (lo >> 7) & 0xFFu;
    if (lo == 0u || (e >= 90u && e <= 140u)) ++pass;
  }
  return pass >= 15;
}

__device__ __forceinline__ float dot2(h2 a, h2 b, float c) {
#if __has_builtin(__builtin_amdgcn_fdot2)
  return __builtin_amdgcn_fdot2(a, b, c, false);
#else
  return fmaf((float)a.x, (float)b.x, fmaf((float)a.y, (float)b.y, c));
#endif
}

__device__ __forceinline__ h2 pk(float a, float b) {
  // v_cvt_pkrtz_f16_f32; builtin returns __fp16v2 — bitcast to _Float16v2
  auto t = __builtin_amdgcn_cvt_pkrtz(a, b);
  h2 r;
  __builtin_memcpy(&r, &t, sizeof(r));
  return r;
}

__device__ __forceinline__ h2 relu2(h2 a) {
  h2 z = {(_Float16)0.0f, (_Float16)0.0f};
#if __has_builtin(__builtin_elementwise_max)
  return __builtin_elementwise_max(a, z);  // v_pk_max_f16
#else
  h2 r;
  r.x = a.x > z.x ? a.x : z.x;
  r.y = a.y > z.y ? a.y : z.y;
  return r;
#endif
}

__device__ __forceinline__ float fexp2(float x) {
#if __has_builtin(__builtin_amdgcn_exp2f)
  return __builtin_amdgcn_exp2f(x);
#else
  return __builtin_exp2f(x);
#endif
}

// ---- prep: sniff dtypes, build fp32-bias + half2-weight tables in d_ws.
// Runs every call (d_ws re-poisoned before each timed launch). ----
__global__ void mpt_prep(const void* __restrict__ cls,
                         const void* __restrict__ Wqkv,
                         const void* __restrict__ bqkv,
                         const void* __restrict__ Wo,
                         const void* __restrict__ bo,
                         const void* __restrict__ W1,
                         const void* __restrict__ b1,
                         const void* __restrict__ W2,
                         const void* __restrict__ b2,
                         const void* __restrict__ xin,
                         float* __restrict__ wf) {
  const bool wbf = is_bf16_packed((const unsigned int*)Wqkv);
  const bool xbf = is_bf16_packed((const unsigned int*)xin);
  // log2(e)/sqrt(2): folds the 1/sqrt(hd) score scale and exp->exp2.
  const float FS = 1.44269504088896341f * 0.70710678118654752f;

  for (int w = threadIdx.x; w < WF_TOTAL; w += 256) {
    if (w == WF_FLAG) { ((int*)wf)[w] = xbf ? 0 : 1; continue; }

    auto g = [&](const void* src, int idx) -> float {
      return wbf ? bf2f(((const unsigned short*)src)[idx])
                 : ((const float*)src)[idx];
    };

    if (w < H_B1) {  // fp32 region
      float val;
      if (w < WF_BQKV) {                       // cls + PE row0 {0,1,0,1}
        val = g(cls, w) + ((w & 1) ? 1.0f : 0.0f);
      } else if (w < WF_BO) {                  // bqkv, scale k rows
        int t = w - WF_BQKV;
        val = g(bqkv, t);
        int j = t % 12;
        if (j >= 4 && j < 8) val *= FS;
      } else if (w < WF_B2) {
        val = g(bo, w - WF_BO);
      } else {
        val = g(b2, w - WF_B2);
      }
      wf[w] = val;
    } else {  // half2 regions
      if (w < H_QKV) {           // b1 pairs: l*8 + p -> (b1[2p], b1[2p+1])
        int t = w - H_B1, l = t / 8, p = t % 8;
        int base = l * 16 + 2 * p;
        ((h2*)wf)[w] = pk(g(b1, base), g(b1, base + 1));
      } else if (w < H_WO) {     // Wqkv: l*48 + j*4 + p*2
        int t = w - H_QKV, l = t / 24, j = (t % 24) / 2, p = t & 1;
        int base = l * 48 + j * 4 + p * 2;
        float s = (j >= 4 && j < 8) ? FS : 1.0f;
        ((h2*)wf)[w] = pk(g(Wqkv, base) * s, g(Wqkv, base + 1) * s);
      } else if (w < H_W1) {     // Wo: l*16 + i*4 + p*2
        int t = w - H_WO, l = t / 8, i = (t % 8) / 2, p = t & 1;
        int base = l * 16 + i * 4 + p * 2;
        ((h2*)wf)[w] = pk(g(Wo, base), g(Wo, base + 1));
      } else if (w < H_W2) {     // W1 pair-major: (l,p,d) -> W1[2p][d], W1[2p+1][d]
        int t = w - H_W1, l = t / 32, p = (t % 32) / 4, d = t % 4;
        int base = l * 64 + 8 * p + d;
        ((h2*)wf)[w] = pk(g(W1, base), g(W1, base + 4));
      } else {                   // W2: l*64 + i*16 + p*2 (pairs along FF)
        int t = w - H_W2, l = t / 32, i = (t % 32) / 8, p = t % 8;
        int base = l * 64 + i * 16 + p * 2;
        ((h2*)wf)[w] = pk(g(W2, base), g(W2, base + 1));
      }
    }
  }
}

// ---- main: one thread per TWO sequences; x state fp32 in registers; linear
// ops via fdot2 (fp16 operands, fp32 accumulate); FFN hidden via pk_fma_f16. ----
__global__ __launch_bounds__(256) void mpt_main(
    const void* __restrict__ xin,   // (N,16) fp32 (or bf16; flag decides)
    const float* __restrict__ wf,   // prepped tables in d_ws
    float* __restrict__ out,        // [N*4 F_g | N*16 subregion] fp32
    int N) {
  constexpr int U = 2;
  const int n0 = blockIdx.x * 512 + threadIdx.x;
  if (n0 >= N) return;
  const bool has1 = (n0 + 256) < N;
  int nseq[U];
  nseq[0] = n0;
  nseq[1] = has1 ? (n0 + 256) : n0;

  const int xf32 = ((const int*)wf)[WF_FLAG];  // wave-uniform
  const h2* hw = (const h2*)wf;                // word-indexed half2 view

  // PE rows 1..4 (row 0 prefolded into cls by prep)
  const float pe[4][4] = {
    { 0.8414709848078965f, 0.5403023058681398f, 0.0099998333341667f, 0.9999500004166653f },
    { 0.9092974268256817f,-0.4161468365471424f, 0.0199986666933331f, 0.9998000066665778f },
    { 0.1411200080598672f,-0.9899924966004454f, 0.0299955002024957f, 0.9995500337489875f },
    {-0.7568024953079283f,-0.6536436208636119f, 0.0399893341866342f, 0.9992001066609779f }
  };

  float raw[U][16];
  if (xf32) {
#pragma unroll
    for (int u = 0; u < U; ++u) {
      const float4* pf =
          reinterpret_cast<const float4*>((const float*)xin + (size_t)nseq[u] * 16);
#pragma unroll
      for (int r = 0; r < 4; ++r) {
        float4 t = pf[r];
        raw[u][r * 4 + 0] = t.x; raw[u][r * 4 + 1] = t.y;
        raw[u][r * 4 + 2] = t.z; raw[u][r * 4 + 3] = t.w;
      }
    }
  } else {
    struct alignas(16) U8 { unsigned short v[8]; };
#pragma unroll
    for (int u = 0; u < U; ++u) {
      const U8* p =
          reinterpret_cast<const U8*>((const unsigned short*)xin + (size_t)nseq[u] * 16);
      U8 a0 = p[0], a1 = p[1];
#pragma unroll
      for (int j = 0; j < 8; ++j) {
        raw[u][j]     = bf2f(a0.v[j]);
        raw[u][8 + j] = bf2f(a1.v[j]);
      }
    }
  }

  float x[U][5][4];
#pragma unroll
  for (int u = 0; u < U; ++u) {
#pragma unroll
    for (int d = 0; d < 4; ++d) x[u][0][d] = wf[WF_CLS + d];  // cls+PE0 prefolded
#pragma unroll
    for (int r = 0; r < 4; ++r)
#pragma unroll
      for (int d = 0; d < 4; ++d) x[u][1 + r][d] = raw[u][r * 4 + d] + pe[r][d];
  }

#pragma unroll 1  // keep code size ~1/3; per-layer scalar ptr math is cheap SALU
  for (int l = 0; l < 3; ++l) {
    const float* bq  = wf + WF_BQKV + l * 12;
    const float* bo  = wf + WF_BO   + l * 4;
    const float* b2  = wf + WF_B2   + l * 4;
    const h2* hb1  = hw + H_B1  + l * 8;   // [p] = (b1[2p], b1[2p+1])
    const h2* hq   = hw + H_QKV + l * 24;  // [j*2 + p]
    const h2* hwo  = hw + H_WO  + l * 8;   // [i*2 + p]
    const h2* hw1p = hw + H_W1  + l * 32;  // [p*4 + d] = (W1[2p][d], W1[2p+1][d])
    const h2* hw2  = hw + H_W2  + l * 32;  // [i*8 + p]

    // pack x rows to half2 pairs
    h2 xh[U][5][2];
#pragma unroll
    for (int s = 0; s < 5; ++s)
#pragma unroll
      for (int u = 0; u < U; ++u) {
        xh[u][s][0] = pk(x[u][s][0], x[u][s][1]);
        xh[u][s][1] = pk(x[u][s][2], x[u][s][3]);
      }

    // qkv projection: 2 chained fdot2 per output (k rows pre-scaled, log2 units)
    float q[U][5][4], k[U][5][4], v[U][5][4];
#pragma unroll
    for (int s = 0; s < 5; ++s) {
#pragma unroll
      for (int j = 0; j < 12; ++j) {
#pragma unroll
        for (int u = 0; u < U; ++u) {
          float a = dot2(xh[u][s][0], hq[j * 2],
                         dot2(xh[u][s][1], hq[j * 2 + 1], bq[j]));
          if (j < 4)      q[u][s][j] = a;
          else if (j < 8) k[u][s][j - 4] = a;
          else            v[u][s][j - 8] = a;
        }
      }
    }

    // attention: head h uses dims {2h,2h+1}; score = fdot2(qh,kh), exp2 domain
    float o[U][5][4];
#pragma unroll
    for (int h = 0; h < 2; ++h) {
      const int d0 = 2 * h, d1 = 2 * h + 1;
      h2 qh[U][5], kh[U][5];
#pragma unroll
      for (int s = 0; s < 5; ++s)
#pragma unroll
        for (int u = 0; u < U; ++u) {
          qh[u][s] = pk(q[u][s][d0], q[u][s][d1]);
          kh[u][s] = pk(k[u][s][d0], k[u][s][d1]);
        }
#pragma unroll
      for (int si = 0; si < 5; ++si) {
        float e[U][5], den[U];
#pragma unroll
        for (int u = 0; u < U; ++u) den[u] = 0.f;
#pragma unroll
        for (int sj = 0; sj < 5; ++sj)
#pragma unroll
          for (int u = 0; u < U; ++u) {
            e[u][sj] = fexp2(dot2(qh[u][si], kh[u][sj], 0.0f));
            den[u] += e[u][sj];
          }
#pragma unroll
        for (int u = 0; u < U; ++u) {
          float inv = __builtin_amdgcn_rcpf(den[u]);
          float o0 = 0.f, o1 = 0.f;
#pragma unroll
          for (int sj = 0; sj < 5; ++sj) {
            o0 = fmaf(e[u][sj], v[u][sj][d0], o0);
            o1 = fmaf(e[u][sj], v[u][sj][d1], o1);
          }
          o[u][si][d0] = o0 * inv;
          o[u][si][d1] = o1 * inv;
        }
      }
    }

    // out-proj + residual, then FFN (packed-fp16 hidden) + residual
#pragma unroll
    for (int s = 0; s < 5; ++s) {
      float nx[U][4];
#pragma unroll
      for (int u = 0; u < U; ++u) {
        h2 oh0 = pk(o[u][s][0], o[u][s][1]), oh1 = pk(o[u][s][2], o[u][s][3]);
#pragma unroll
        for (int i = 0; i < 4; ++i)
          nx[u][i] = dot2(oh0, hwo[i * 2],
                          dot2(oh1, hwo[i * 2 + 1], x[u][s][i] + bo[i]));
      }

      // broadcast pairs of nx for pk_fma; acc fp32 via dot2
      h2 xb[U][4];
      float acc[U][4];
#pragma unroll
      for (int u = 0; u < U; ++u) {
#pragma unroll
        for (int d = 0; d < 4; ++d) xb[u][d] = pk(nx[u][d], nx[u][d]);
#pragma unroll
        for (int i = 0; i < 4; ++i) acc[u][i] = b2[i];
      }
#pragma unroll
      for (int p = 0; p < 8; ++p) {
        h2 hh[U];
#pragma unroll
        for (int u = 0; u < U; ++u) {
          h2 hc = hb1[p];
#pragma unroll
          for (int d = 0; d < 4; ++d) hc = xb[u][d] * hw1p[p * 4 + d] + hc;  // v_pk_fma_f16
          hh[u] = relu2(hc);  // v_pk_max_f16
        }
#pragma unroll
        for (int u = 0; u < U; ++u)
#pragma unroll
          for (int i = 0; i < 4; ++i)
            acc[u][i] = dot2(hh[u], hw2[i * 8 + p], acc[u][i]);
      }
#pragma unroll
      for (int u = 0; u < U; ++u)
#pragma unroll
        for (int i = 0; i < 4; ++i) x[u][s][i] = nx[u][i] + acc[u][i];
    }
  }

  // stores (fp32, coalesced dwordx4)
#pragma unroll
  for (int u = 0; u < U; ++u) {
    if (u == 1 && !has1) break;
    const int n = nseq[u];
    *reinterpret_cast<float4*>(out + (size_t)n * 4) =
        make_float4(x[u][0][0], x[u][0][1], x[u][0][2], x[u][0][3]);
    float* sub = out + (size_t)N * 4 + (size_t)n * 16;
#pragma unroll
    for (int r = 0; r < 4; ++r)
      *reinterpret_cast<float4*>(sub + r * 4) =
          make_float4(x[u][1 + r][0], x[u][1 + r][1], x[u][1 + r][2], x[u][1 + r][3]);
  }
}

extern "C" void kernel_launch(void* const* d_in, const int* in_sizes, int n_in,
                              void* d_out, int out_size, void* d_ws, size_t ws_size,
                              hipStream_t stream) {
  float* wf = (float*)d_ws;

  mpt_prep<<<1, 256, 0, stream>>>(
      d_in[1], d_in[2], d_in[3], d_in[4], d_in[5],
      d_in[6], d_in[7], d_in[8], d_in[9],
      d_in[0],  // regional_states (dtype sniff)
      wf);

  const int N = in_sizes[0] / 16;  // B*T sequences
  mpt_main<<<(N + 511) / 512, 256, 0, stream>>>(
      d_in[0], wf, (float*)d_out, N);
}

// Round 2
// 265.916 us; speedup vs baseline: 1.0373x; 1.0032x over previous
//
#include <hip/hip_runtime.h>

// MetaPolicyTransformer: B=65536,T=20,M=4,D=4,L=3,H=2,FF=16,S=5. N=B*T seqs.
// R8 = R7 + __launch_bounds__(256, 2) on mpt_main.
// Rationale: R6/R7 VGPR counts (52/104) sit exactly at occupancy-tier edges
// while live state (~160 fp32 at the qkv->attn boundary) far exceeds them ->
// the allocator is buying occupancy tiers (4-8 waves/SIMD) with live-range
// splits + remat, inflating issue count ~1.9x over hand-count. Measured
// resident occupancy is only ~1.65 waves/SIMD, so that occupancy is never
// used. (256,2) targets 2 waves/EU -> VGPR budget 256, freeing the scheduler.
// R7: TWO sequences per thread; FFN hidden via packed fp16 (v_pk_fma_f16 +
// v_pk_max_f16, b1 pre-packed h2); layer loop not unrolled (I$ control).
// Carried from R3-R6: 1 thread = full sequence, uniform s_load weights,
// v_dot2_f32_f16 linear algebra, exp2-domain attention (log2e/sqrt2 folded
// into Wk/bk by prep), no softmax max-subtract (scores bounded).

typedef _Float16 h2 __attribute__((ext_vector_type(2)));

// d_ws word layout (4-byte words; fp32 or half2 per word)
enum {
  WF_CLS  = 0,    // 4   fp32: cls + PE row 0 prefolded
  WF_BQKV = 4,    // 36  fp32 biases, k-part pre-scaled by log2e/sqrt2
  WF_BO   = 40,   // 12
  WF_B2   = 52,   // 12
  H_B1    = 64,   // 24  half2: (l,p) = (b1[2p], b1[2p+1])
  H_QKV   = 88,   // 72  half2: (l,row j,pair p) Wqkv[j][2p],[2p+1]; k rows scaled
  H_WO    = 160,  // 24  half2: (l,i,p)
  H_W1    = 184,  // 96  half2 PAIR-MAJOR: (l,p,d) = (W1[2p][d], W1[2p+1][d])
  H_W2    = 280,  // 96  half2: (l,i,fpair p) W2[i][2p],[2p+1]
  WF_FLAG = 376,  // int: 1 if regional_states fp32
  WF_TOTAL = 377
};

__device__ __forceinline__ float bf2f(unsigned short u) {
  unsigned int x = ((unsigned int)u) << 16;
  float f;
  __builtin_memcpy(&f, &x, 4);
  return f;
}

__device__ __forceinline__ bool is_bf16_packed(const unsigned int* w) {
  int pass = 0;
#pragma unroll
  for (int i = 0; i < 16; ++i) {
    unsigned int lo = w[i] & 0xFFFFu;
    unsigned int e = (lo >> 7) & 0xFFu;
    if (lo == 0u || (e >= 90u && e <= 140u)) ++pass;
  }
  return pass >= 15;
}

__device__ __forceinline__ float dot2(h2 a, h2 b, float c) {
#if __has_builtin(__builtin_amdgcn_fdot2)
  return __builtin_amdgcn_fdot2(a, b, c, false);
#else
  return fmaf((float)a.x, (float)b.x, fmaf((float)a.y, (float)b.y, c));
#endif
}

__device__ __forceinline__ h2 pk(float a, float b) {
  // v_cvt_pkrtz_f16_f32; builtin returns __fp16v2 — bitcast to _Float16v2
  auto t = __builtin_amdgcn_cvt_pkrtz(a, b);
  h2 r;
  __builtin_memcpy(&r, &t, sizeof(r));
  return r;
}

__device__ __forceinline__ h2 relu2(h2 a) {
  h2 z = {(_Float16)0.0f, (_Float16)0.0f};
#if __has_builtin(__builtin_elementwise_max)
  return __builtin_elementwise_max(a, z);  // v_pk_max_f16
#else
  h2 r;
  r.x = a.x > z.x ? a.x : z.x;
  r.y = a.y > z.y ? a.y : z.y;
  return r;
#endif
}

__device__ __forceinline__ float fexp2(float x) {
#if __has_builtin(__builtin_amdgcn_exp2f)
  return __builtin_amdgcn_exp2f(x);
#else
  return __builtin_exp2f(x);
#endif
}

// ---- prep: sniff dtypes, build fp32-bias + half2-weight tables in d_ws.
// Runs every call (d_ws re-poisoned before each timed launch). ----
__global__ void mpt_prep(const void* __restrict__ cls,
                         const void* __restrict__ Wqkv,
                         const void* __restrict__ bqkv,
                         const void* __restrict__ Wo,
                         const void* __restrict__ bo,
                         const void* __restrict__ W1,
                         const void* __restrict__ b1,
                         const void* __restrict__ W2,
                         const void* __restrict__ b2,
                         const void* __restrict__ xin,
                         float* __restrict__ wf) {
  const bool wbf = is_bf16_packed((const unsigned int*)Wqkv);
  const bool xbf = is_bf16_packed((const unsigned int*)xin);
  // log2(e)/sqrt(2): folds the 1/sqrt(hd) score scale and exp->exp2.
  const float FS = 1.44269504088896341f * 0.70710678118654752f;

  for (int w = threadIdx.x; w < WF_TOTAL; w += 256) {
    if (w == WF_FLAG) { ((int*)wf)[w] = xbf ? 0 : 1; continue; }

    auto g = [&](const void* src, int idx) -> float {
      return wbf ? bf2f(((const unsigned short*)src)[idx])
                 : ((const float*)src)[idx];
    };

    if (w < H_B1) {  // fp32 region
      float val;
      if (w < WF_BQKV) {                       // cls + PE row0 {0,1,0,1}
        val = g(cls, w) + ((w & 1) ? 1.0f : 0.0f);
      } else if (w < WF_BO) {                  // bqkv, scale k rows
        int t = w - WF_BQKV;
        val = g(bqkv, t);
        int j = t % 12;
        if (j >= 4 && j < 8) val *= FS;
      } else if (w < WF_B2) {
        val = g(bo, w - WF_BO);
      } else {
        val = g(b2, w - WF_B2);
      }
      wf[w] = val;
    } else {  // half2 regions
      if (w < H_QKV) {           // b1 pairs: l*8 + p -> (b1[2p], b1[2p+1])
        int t = w - H_B1, l = t / 8, p = t % 8;
        int base = l * 16 + 2 * p;
        ((h2*)wf)[w] = pk(g(b1, base), g(b1, base + 1));
      } else if (w < H_WO) {     // Wqkv: l*48 + j*4 + p*2
        int t = w - H_QKV, l = t / 24, j = (t % 24) / 2, p = t & 1;
        int base = l * 48 + j * 4 + p * 2;
        float s = (j >= 4 && j < 8) ? FS : 1.0f;
        ((h2*)wf)[w] = pk(g(Wqkv, base) * s, g(Wqkv, base + 1) * s);
      } else if (w < H_W1) {     // Wo: l*16 + i*4 + p*2
        int t = w - H_WO, l = t / 8, i = (t % 8) / 2, p = t & 1;
        int base = l * 16 + i * 4 + p * 2;
        ((h2*)wf)[w] = pk(g(Wo, base), g(Wo, base + 1));
      } else if (w < H_W2) {     // W1 pair-major: (l,p,d) -> W1[2p][d], W1[2p+1][d]
        int t = w - H_W1, l = t / 32, p = (t % 32) / 4, d = t % 4;
        int base = l * 64 + 8 * p + d;
        ((h2*)wf)[w] = pk(g(W1, base), g(W1, base + 4));
      } else {                   // W2: l*64 + i*16 + p*2 (pairs along FF)
        int t = w - H_W2, l = t / 32, i = (t % 32) / 8, p = t % 8;
        int base = l * 64 + i * 16 + p * 2;
        ((h2*)wf)[w] = pk(g(W2, base), g(W2, base + 1));
      }
    }
  }
}

// ---- main: one thread per TWO sequences; x state fp32 in registers; linear
// ops via fdot2 (fp16 operands, fp32 accumulate); FFN hidden via pk_fma_f16.
// __launch_bounds__(256, 2): target 2 waves/EU -> VGPR budget 256; stops the
// allocator from squeezing ~160 live values into a 4-wave (128 VGPR) tier
// with remat/splits (measured resident occupancy is only ~1.65 waves/SIMD,
// so the squeezed occupancy was never realized). ----
__global__ __launch_bounds__(256, 2) void mpt_main(
    const void* __restrict__ xin,   // (N,16) fp32 (or bf16; flag decides)
    const float* __restrict__ wf,   // prepped tables in d_ws
    float* __restrict__ out,        // [N*4 F_g | N*16 subregion] fp32
    int N) {
  constexpr int U = 2;
  const int n0 = blockIdx.x * 512 + threadIdx.x;
  if (n0 >= N) return;
  const bool has1 = (n0 + 256) < N;
  int nseq[U];
  nseq[0] = n0;
  nseq[1] = has1 ? (n0 + 256) : n0;

  const int xf32 = ((const int*)wf)[WF_FLAG];  // wave-uniform
  const h2* hw = (const h2*)wf;                // word-indexed half2 view

  // PE rows 1..4 (row 0 prefolded into cls by prep)
  const float pe[4][4] = {
    { 0.8414709848078965f, 0.5403023058681398f, 0.0099998333341667f, 0.9999500004166653f },
    { 0.9092974268256817f,-0.4161468365471424f, 0.0199986666933331f, 0.9998000066665778f },
    { 0.1411200080598672f,-0.9899924966004454f, 0.0299955002024957f, 0.9995500337489875f },
    {-0.7568024953079283f,-0.6536436208636119f, 0.0399893341866342f, 0.9992001066609779f }
  };

  float raw[U][16];
  if (xf32) {
#pragma unroll
    for (int u = 0; u < U; ++u) {
      const float4* pf =
          reinterpret_cast<const float4*>((const float*)xin + (size_t)nseq[u] * 16);
#pragma unroll
      for (int r = 0; r < 4; ++r) {
        float4 t = pf[r];
        raw[u][r * 4 + 0] = t.x; raw[u][r * 4 + 1] = t.y;
        raw[u][r * 4 + 2] = t.z; raw[u][r * 4 + 3] = t.w;
      }
    }
  } else {
    struct alignas(16) U8 { unsigned short v[8]; };
#pragma unroll
    for (int u = 0; u < U; ++u) {
      const U8* p =
          reinterpret_cast<const U8*>((const unsigned short*)xin + (size_t)nseq[u] * 16);
      U8 a0 = p[0], a1 = p[1];
#pragma unroll
      for (int j = 0; j < 8; ++j) {
        raw[u][j]     = bf2f(a0.v[j]);
        raw[u][8 + j] = bf2f(a1.v[j]);
      }
    }
  }

  float x[U][5][4];
#pragma unroll
  for (int u = 0; u < U; ++u) {
#pragma unroll
    for (int d = 0; d < 4; ++d) x[u][0][d] = wf[WF_CLS + d];  // cls+PE0 prefolded
#pragma unroll
    for (int r = 0; r < 4; ++r)
#pragma unroll
      for (int d = 0; d < 4; ++d) x[u][1 + r][d] = raw[u][r * 4 + d] + pe[r][d];
  }

#pragma unroll 1  // keep code size ~1/3; per-layer scalar ptr math is cheap SALU
  for (int l = 0; l < 3; ++l) {
    const float* bq  = wf + WF_BQKV + l * 12;
    const float* bo  = wf + WF_BO   + l * 4;
    const float* b2  = wf + WF_B2   + l * 4;
    const h2* hb1  = hw + H_B1  + l * 8;   // [p] = (b1[2p], b1[2p+1])
    const h2* hq   = hw + H_QKV + l * 24;  // [j*2 + p]
    const h2* hwo  = hw + H_WO  + l * 8;   // [i*2 + p]
    const h2* hw1p = hw + H_W1  + l * 32;  // [p*4 + d] = (W1[2p][d], W1[2p+1][d])
    const h2* hw2  = hw + H_W2  + l * 32;  // [i*8 + p]

    // pack x rows to half2 pairs
    h2 xh[U][5][2];
#pragma unroll
    for (int s = 0; s < 5; ++s)
#pragma unroll
      for (int u = 0; u < U; ++u) {
        xh[u][s][0] = pk(x[u][s][0], x[u][s][1]);
        xh[u][s][1] = pk(x[u][s][2], x[u][s][3]);
      }

    // qkv projection: 2 chained fdot2 per output (k rows pre-scaled, log2 units)
    float q[U][5][4], k[U][5][4], v[U][5][4];
#pragma unroll
    for (int s = 0; s < 5; ++s) {
#pragma unroll
      for (int j = 0; j < 12; ++j) {
#pragma unroll
        for (int u = 0; u < U; ++u) {
          float a = dot2(xh[u][s][0], hq[j * 2],
                         dot2(xh[u][s][1], hq[j * 2 + 1], bq[j]));
          if (j < 4)      q[u][s][j] = a;
          else if (j < 8) k[u][s][j - 4] = a;
          else            v[u][s][j - 8] = a;
        }
      }
    }

    // attention: head h uses dims {2h,2h+1}; score = fdot2(qh,kh), exp2 domain
    float o[U][5][4];
#pragma unroll
    for (int h = 0; h < 2; ++h) {
      const int d0 = 2 * h, d1 = 2 * h + 1;
      h2 qh[U][5], kh[U][5];
#pragma unroll
      for (int s = 0; s < 5; ++s)
#pragma unroll
        for (int u = 0; u < U; ++u) {
          qh[u][s] = pk(q[u][s][d0], q[u][s][d1]);
          kh[u][s] = pk(k[u][s][d0], k[u][s][d1]);
        }
#pragma unroll
      for (int si = 0; si < 5; ++si) {
        float e[U][5], den[U];
#pragma unroll
        for (int u = 0; u < U; ++u) den[u] = 0.f;
#pragma unroll
        for (int sj = 0; sj < 5; ++sj)
#pragma unroll
          for (int u = 0; u < U; ++u) {
            e[u][sj] = fexp2(dot2(qh[u][si], kh[u][sj], 0.0f));
            den[u] += e[u][sj];
          }
#pragma unroll
        for (int u = 0; u < U; ++u) {
          float inv = __builtin_amdgcn_rcpf(den[u]);
          float o0 = 0.f, o1 = 0.f;
#pragma unroll
          for (int sj = 0; sj < 5; ++sj) {
            o0 = fmaf(e[u][sj], v[u][sj][d0], o0);
            o1 = fmaf(e[u][sj], v[u][sj][d1], o1);
          }
          o[u][si][d0] = o0 * inv;
          o[u][si][d1] = o1 * inv;
        }
      }
    }

    // out-proj + residual, then FFN (packed-fp16 hidden) + residual
#pragma unroll
    for (int s = 0; s < 5; ++s) {
      float nx[U][4];
#pragma unroll
      for (int u = 0; u < U; ++u) {
        h2 oh0 = pk(o[u][s][0], o[u][s][1]), oh1 = pk(o[u][s][2], o[u][s][3]);
#pragma unroll
        for (int i = 0; i < 4; ++i)
          nx[u][i] = dot2(oh0, hwo[i * 2],
                          dot2(oh1, hwo[i * 2 + 1], x[u][s][i] + bo[i]));
      }

      // broadcast pairs of nx for pk_fma; acc fp32 via dot2
      h2 xb[U][4];
      float acc[U][4];
#pragma unroll
      for (int u = 0; u < U; ++u) {
#pragma unroll
        for (int d = 0; d < 4; ++d) xb[u][d] = pk(nx[u][d], nx[u][d]);
#pragma unroll
        for (int i = 0; i < 4; ++i) acc[u][i] = b2[i];
      }
#pragma unroll
      for (int p = 0; p < 8; ++p) {
        h2 hh[U];
#pragma unroll
        for (int u = 0; u < U; ++u) {
          h2 hc = hb1[p];
#pragma unroll
          for (int d = 0; d < 4; ++d) hc = xb[u][d] * hw1p[p * 4 + d] + hc;  // v_pk_fma_f16
          hh[u] = relu2(hc);  // v_pk_max_f16
        }
#pragma unroll
        for (int u = 0; u < U; ++u)
#pragma unroll
          for (int i = 0; i < 4; ++i)
            acc[u][i] = dot2(hh[u], hw2[i * 8 + p], acc[u][i]);
      }
#pragma unroll
      for (int u = 0; u < U; ++u)
#pragma unroll
        for (int i = 0; i < 4; ++i) x[u][s][i] = nx[u][i] + acc[u][i];
    }
  }

  // stores (fp32, coalesced dwordx4)
#pragma unroll
  for (int u = 0; u < U; ++u) {
    if (u == 1 && !has1) break;
    const int n = nseq[u];
    *reinterpret_cast<float4*>(out + (size_t)n * 4) =
        make_float4(x[u][0][0], x[u][0][1], x[u][0][2], x[u][0][3]);
    float* sub = out + (size_t)N * 4 + (size_t)n * 16;
#pragma unroll
    for (int r = 0; r < 4; ++r)
      *reinterpret_cast<float4*>(sub + r * 4) =
          make_float4(x[u][1 + r][0], x[u][1 + r][1], x[u][1 + r][2], x[u][1 + r][3]);
  }
}

extern "C" void kernel_launch(void* const* d_in, const int* in_sizes, int n_in,
                              void* d_out, int out_size, void* d_ws, size_t ws_size,
                              hipStream_t stream) {
  float* wf = (float*)d_ws;

  mpt_prep<<<1, 256, 0, stream>>>(
      d_in[1], d_in[2], d_in[3], d_in[4], d_in[5],
      d_in[6], d_in[7], d_in[8], d_in[9],
      d_in[0],  // regional_states (dtype sniff)
      wf);

  const int N = in_sizes[0] / 16;  // B*T sequences
  mpt_main<<<(N + 511) / 512, 256, 0, stream>>>(
      d_in[0], wf, (float*)d_out, N);
}